// Round 1
// baseline (1851.389 us; speedup 1.0000x reference)
//
#include <hip/hip_runtime.h>

#define N_NODES 100000
#define N_EDGES 1600000
#define DF 128
#define NL 3
#define NG 128
#define NC 2
#define BN_EPS 1e-5f
#define STATS_BLOCKS 256

// ---------------- CSR build ----------------

__global__ void zero_ints_kernel(int* p, int n) {
    int i = blockIdx.x * blockDim.x + threadIdx.x;
    if (i < n) p[i] = 0;
}

__global__ void count_deg_kernel(const int* __restrict__ dst, int* __restrict__ deg) {
    int e = blockIdx.x * blockDim.x + threadIdx.x;
    if (e < N_EDGES) atomicAdd(&deg[dst[e]], 1);
}

// single-block exclusive scan over deg -> offsets (N+1 entries)
__global__ void scan_offsets_kernel(const int* __restrict__ deg, int* __restrict__ offsets) {
    __shared__ int buf[1024];
    __shared__ int carry_s;
    int tid = threadIdx.x;
    if (tid == 0) carry_s = 0;
    __syncthreads();
    for (int base = 0; base < N_NODES; base += 1024) {
        int i = base + tid;
        int v = (i < N_NODES) ? deg[i] : 0;
        buf[tid] = v;
        __syncthreads();
        for (int off = 1; off < 1024; off <<= 1) {
            int t = (tid >= off) ? buf[tid - off] : 0;
            __syncthreads();
            buf[tid] += t;
            __syncthreads();
        }
        if (i < N_NODES) offsets[i] = carry_s + buf[tid] - v;
        __syncthreads();
        if (tid == 0) carry_s += buf[1023];
        __syncthreads();
    }
    if (tid == 0) offsets[N_NODES] = carry_s;
}

__global__ void fill_adj_kernel(const int* __restrict__ src, const int* __restrict__ dst,
                                const int* __restrict__ offsets, int* __restrict__ cursor,
                                int* __restrict__ adj) {
    int e = blockIdx.x * blockDim.x + threadIdx.x;
    if (e < N_EDGES) {
        int d = dst[e];
        int p = atomicAdd(&cursor[d], 1);
        adj[offsets[d] + p] = src[e];
    }
}

// ---------------- aggregation: out[i] = x[i] + sum_{e: dst=i} x[src[e]] ----------------

__global__ void agg_kernel(const float* __restrict__ X, const int* __restrict__ offsets,
                           const int* __restrict__ adj, float* __restrict__ out) {
    int i = blockIdx.x;
    int f = threadIdx.x;   // 128 threads = 128 features
    float s = X[(size_t)i * DF + f];
    int b = offsets[i], e = offsets[i + 1];
    for (int k = b; k < e; k++) {
        int sidx = adj[k];
        s += X[(size_t)sidx * DF + f];
    }
    out[(size_t)i * DF + f] = s;
}

// ---------------- fp32 GEMM: out[N x 128] = A[N x 128] @ W[128 x 128] + bias ----------------

__global__ __launch_bounds__(256) void gemm128_kernel(const float* __restrict__ A,
                                                      const float* __restrict__ W,
                                                      const float* __restrict__ bias,
                                                      float* __restrict__ out, int nrows) {
    __shared__ float Ws[128 * 128];     // full W, row-major [k][j]
    __shared__ float As[16][132];       // transposed A chunk [kk][row], padded

    int tid = threadIdx.x;
    // cooperative load of W (4096 float4)
    const float4* W4 = (const float4*)W;
    float4* Ws4 = (float4*)Ws;
#pragma unroll
    for (int i = 0; i < 16; i++) Ws4[tid + i * 256] = W4[tid + i * 256];

    int rb = blockIdx.x * 128;
    int ty = tid >> 4, tx = tid & 15;   // 16x16 thread grid, 8x8 outputs each

    float acc[8][8];
#pragma unroll
    for (int i = 0; i < 8; i++)
#pragma unroll
        for (int j = 0; j < 8; j++) acc[i][j] = 0.f;

    for (int kc = 0; kc < 128; kc += 16) {
        __syncthreads();
        // stage A[rb..rb+127][kc..kc+15] transposed into As
#pragma unroll
        for (int i = 0; i < 2; i++) {
            int q = tid + i * 256;        // 0..511
            int row = q >> 2, quad = q & 3;
            int grow = rb + row;
            float4 v = make_float4(0.f, 0.f, 0.f, 0.f);
            if (grow < nrows) v = *(const float4*)&A[(size_t)grow * DF + kc + quad * 4];
            As[quad * 4 + 0][row] = v.x;
            As[quad * 4 + 1][row] = v.y;
            As[quad * 4 + 2][row] = v.z;
            As[quad * 4 + 3][row] = v.w;
        }
        __syncthreads();
#pragma unroll
        for (int kk = 0; kk < 16; kk++) {
            float a[8], b[8];
            *(float4*)&a[0] = *(const float4*)&As[kk][ty * 8];
            *(float4*)&a[4] = *(const float4*)&As[kk][ty * 8 + 4];
            *(float4*)&b[0] = *(const float4*)&Ws[(kc + kk) * 128 + tx * 8];
            *(float4*)&b[4] = *(const float4*)&Ws[(kc + kk) * 128 + tx * 8 + 4];
#pragma unroll
            for (int i = 0; i < 8; i++)
#pragma unroll
                for (int j = 0; j < 8; j++) acc[i][j] += a[i] * b[j];
        }
    }

#pragma unroll
    for (int i = 0; i < 8; i++) {
        int grow = rb + ty * 8 + i;
        if (grow < nrows) {
#pragma unroll
            for (int j = 0; j < 8; j += 4) {
                int col = tx * 8 + j;
                float4 o;
                o.x = acc[i][j + 0] + bias[col + 0];
                o.y = acc[i][j + 1] + bias[col + 1];
                o.z = acc[i][j + 2] + bias[col + 2];
                o.w = acc[i][j + 3] + bias[col + 3];
                *(float4*)&out[(size_t)grow * DF + col] = o;
            }
        }
    }
}

// ---------------- BN statistics (two-stage, deterministic) ----------------

__global__ __launch_bounds__(256) void bn_stats_kernel(const float* __restrict__ H,
                                                       float* __restrict__ psum,
                                                       float* __restrict__ psq) {
    int tid = threadIdx.x;
    size_t idx = (size_t)blockIdx.x * 256 + tid;
    const size_t stride = (size_t)STATS_BLOCKS * 256;
    const size_t total = (size_t)N_NODES * DF;
    float s = 0.f, q = 0.f;
    for (size_t p = idx; p < total; p += stride) {
        float v = H[p];
        s += v;
        q += v * v;
    }
    __shared__ float ls[256], lq[256];
    ls[tid] = s; lq[tid] = q;
    __syncthreads();
    if (tid < 128) {
        float ss = ls[tid] + ls[tid + 128];
        float qq = lq[tid] + lq[tid + 128];
        psum[blockIdx.x * 128 + tid] = ss;
        psq[blockIdx.x * 128 + tid] = qq;
    }
}

// mode 0: scale = rsqrt(v+eps)*g ; shift = bt - m*scale          (BN1, to fold into W2)
// mode 1: compose BN2 with outer BN: r2=rsqrt(v+eps); a=r2*g; vu=v*a*a; r3=rsqrt(vu+eps);
//         scale = a*r3*og ; shift = ob - m*scale                  (bt2 cancels exactly)
__global__ void bn_finalize_kernel(const float* __restrict__ psum, const float* __restrict__ psq,
                                   const float* __restrict__ g, const float* __restrict__ bt,
                                   const float* __restrict__ og, const float* __restrict__ ob,
                                   float* __restrict__ scale, float* __restrict__ shift, int mode) {
    int f = threadIdx.x;  // 128 threads
    float s = 0.f, q = 0.f;
    for (int b = 0; b < STATS_BLOCKS; b++) {
        s += psum[b * 128 + f];
        q += psq[b * 128 + f];
    }
    float m = s / (float)N_NODES;
    float v = q / (float)N_NODES - m * m;
    if (v < 0.f) v = 0.f;
    float sc, sh;
    if (mode == 0) {
        float r = rsqrtf(v + BN_EPS);
        sc = r * g[f];
        sh = bt[f] - m * sc;
    } else {
        float r2 = rsqrtf(v + BN_EPS);
        float a = r2 * g[f];
        float vu = v * a * a;
        float r3 = rsqrtf(vu + BN_EPS);
        sc = a * r3 * og[f];
        sh = ob[f] - m * sc;
    }
    scale[f] = sc;
    shift[f] = sh;
}

// W2f[k][j] = scale1[k] * W2[k][j];  b2f[j] = b2[j] + sum_k shift1[k]*W2[k][j]
__global__ void fold_w2_kernel(const float* __restrict__ W2, const float* __restrict__ b2,
                               const float* __restrict__ scale1, const float* __restrict__ shift1,
                               float* __restrict__ W2f, float* __restrict__ b2f) {
    int j = threadIdx.x;  // 128 threads, 1 block
    float acc = b2[j];
    for (int k = 0; k < 128; k++) {
        float w = W2[k * 128 + j];
        W2f[k * 128 + j] = scale1[k] * w;
        acc += shift1[k] * w;
    }
    b2f[j] = acc;
}

__global__ void relu_affine_kernel(const float* __restrict__ H, const float* __restrict__ scale,
                                   const float* __restrict__ shift, float* __restrict__ out) {
    size_t idx = (size_t)blockIdx.x * blockDim.x + threadIdx.x;
    if (idx < (size_t)N_NODES * DF) {
        int f = (int)(idx & (DF - 1));
        float y = H[idx] * scale[f] + shift[f];
        out[idx] = y > 0.f ? y : 0.f;
    }
}

// ---------------- readout ----------------

__global__ void graph_embed_kernel(const float* __restrict__ X, const float* __restrict__ w,
                                   const int* __restrict__ batch, float* __restrict__ ge) {
    int g = blockIdx.x;
    int f = threadIdx.x;  // 128
    int lo = 0, hi = N_NODES;
    while (lo < hi) { int mid = (lo + hi) >> 1; if (batch[mid] < g) lo = mid + 1; else hi = mid; }
    int s = lo;
    lo = 0; hi = N_NODES;
    while (lo < hi) { int mid = (lo + hi) >> 1; if (batch[mid] < g + 1) lo = mid + 1; else hi = mid; }
    int e = lo;
    float acc = 0.f;
    for (int r = s; r < e; r++) acc += X[(size_t)r * DF + f] * w[r];
    ge[g * DF + f] = acc;
}

__global__ void final_fc_kernel(const float* __restrict__ ge, const float* __restrict__ fcW,
                                const float* __restrict__ fcb, float* __restrict__ out) {
    int idx = blockIdx.x * blockDim.x + threadIdx.x;  // G*C = 256
    if (idx < NG * NC) {
        int g = idx / NC, c = idx % NC;
        float acc = fcb[c];
        for (int d = 0; d < DF; d++) acc += ge[g * DF + d] * fcW[d * NC + c];
        out[idx] = acc;
    }
}

// ---------------- launcher ----------------

extern "C" void kernel_launch(void* const* d_in, const int* in_sizes, int n_in,
                              void* d_out, int out_size, void* d_ws, size_t ws_size,
                              hipStream_t stream) {
    const float* x    = (const float*)d_in[0];
    const int*   ei   = (const int*)d_in[1];
    const int*   src  = ei;
    const int*   dst  = ei + N_EDGES;
    const float* nw   = (const float*)d_in[2];
    const int*   batch= (const int*)d_in[3];
    const float* W1   = (const float*)d_in[4];
    const float* b1   = (const float*)d_in[5];
    const float* g1   = (const float*)d_in[6];
    const float* bt1  = (const float*)d_in[7];
    const float* W2   = (const float*)d_in[8];
    const float* b2   = (const float*)d_in[9];
    const float* g2   = (const float*)d_in[10];
    const float* bt2  = (const float*)d_in[11];
    const float* og   = (const float*)d_in[12];
    const float* ob   = (const float*)d_in[13];
    const float* fcW  = (const float*)d_in[14];
    const float* fcb  = (const float*)d_in[15];

    float* out_f    = (float*)d_out;
    float* node_out = out_f;                              // N*DF
    float* ge       = out_f + (size_t)N_NODES * DF;       // G*DF
    float* cls      = ge + NG * DF;                       // G*C

    char* w = (char*)d_ws;
    float* B0      = (float*)w;  w += (size_t)N_NODES * DF * sizeof(float);
    int*   deg     = (int*)w;    w += (size_t)N_NODES * sizeof(int);
    int*   cursor  = (int*)w;    w += (size_t)N_NODES * sizeof(int);
    int*   offsets = (int*)w;    w += (size_t)(N_NODES + 1) * sizeof(int);
    w = (char*)(((size_t)w + 15) & ~(size_t)15);
    int*   adj     = (int*)w;    w += (size_t)N_EDGES * sizeof(int);
    float* psum    = (float*)w;  w += (size_t)STATS_BLOCKS * 128 * sizeof(float);
    float* psq     = (float*)w;  w += (size_t)STATS_BLOCKS * 128 * sizeof(float);
    float* scale1  = (float*)w;  w += 128 * sizeof(float);
    float* shift1  = (float*)w;  w += 128 * sizeof(float);
    float* W2f     = (float*)w;  w += 128 * 128 * sizeof(float);
    float* b2f     = (float*)w;  w += 128 * sizeof(float);
    float* scaleO  = (float*)w;  w += 128 * sizeof(float);
    float* shiftO  = (float*)w;  w += 128 * sizeof(float);

    // B1 aliases the node_embeddings region of d_out (dead between layers)
    float* B1 = node_out;

    const int gemm_blocks = (N_NODES + 127) / 128;

    // CSR build (edges identical across layers -> build once)
    zero_ints_kernel<<<(2 * N_NODES + 255) / 256, 256, 0, stream>>>(deg, 2 * N_NODES);
    count_deg_kernel<<<(N_EDGES + 255) / 256, 256, 0, stream>>>(dst, deg);
    scan_offsets_kernel<<<1, 1024, 0, stream>>>(deg, offsets);
    fill_adj_kernel<<<(N_EDGES + 255) / 256, 256, 0, stream>>>(src, dst, offsets, cursor, adj);

    const float* Xcur = x;
    for (int l = 0; l < NL; l++) {
        // agg = X + sum_{in-edges} X[src]
        agg_kernel<<<N_NODES, 128, 0, stream>>>(Xcur, offsets, adj, B0);
        // h1_raw = agg @ W1[l] + b1[l]
        gemm128_kernel<<<gemm_blocks, 256, 0, stream>>>(B0, W1 + (size_t)l * DF * DF,
                                                        b1 + l * DF, B1, N_NODES);
        // BN1 -> fold into W2
        bn_stats_kernel<<<STATS_BLOCKS, 256, 0, stream>>>(B1, psum, psq);
        bn_finalize_kernel<<<1, 128, 0, stream>>>(psum, psq, g1 + l * DF, bt1 + l * DF,
                                                  nullptr, nullptr, scale1, shift1, 0);
        fold_w2_kernel<<<1, 128, 0, stream>>>(W2 + (size_t)l * DF * DF, b2 + l * DF,
                                              scale1, shift1, W2f, b2f);
        // h2_raw = BN1(h1_raw) @ W2[l] + b2[l]  == h1_raw @ W2f + b2f
        gemm128_kernel<<<gemm_blocks, 256, 0, stream>>>(B1, W2f, b2f, B0, N_NODES);
        // BN2 + outer BN composed analytically, then ReLU
        bn_stats_kernel<<<STATS_BLOCKS, 256, 0, stream>>>(B0, psum, psq);
        bn_finalize_kernel<<<1, 128, 0, stream>>>(psum, psq, g2 + l * DF, bt2 + l * DF,
                                                  og + l * DF, ob + l * DF, scaleO, shiftO, 1);
        relu_affine_kernel<<<(int)(((size_t)N_NODES * DF + 255) / 256), 256, 0, stream>>>(
            B0, scaleO, shiftO, node_out);
        Xcur = node_out;
    }

    graph_embed_kernel<<<NG, 128, 0, stream>>>(node_out, nw, batch, ge);
    final_fc_kernel<<<1, 256, 0, stream>>>(ge, fcW, fcb, cls);
}

// Round 2
// 1245.139 us; speedup vs baseline: 1.4869x; 1.4869x over previous
//
#include <hip/hip_runtime.h>

#define N_NODES 100000
#define N_EDGES 1600000
#define DF 128
#define NL 3
#define NG 128
#define NC 2
#define BN_EPS 1e-5f
#define GEMM_BLOCKS ((N_NODES + 127) / 128)   // 782
#define SCAN_BLOCK 1024
#define SCAN_NBLK ((N_NODES + SCAN_BLOCK - 1) / SCAN_BLOCK)  // 98
#define GE_SLICES 16

typedef unsigned int u32;
typedef unsigned short u16;

using bf16x8 = __attribute__((ext_vector_type(8))) short;
using f32x4  = __attribute__((ext_vector_type(4))) float;

__device__ __forceinline__ u16 f2bf(float f) {
    u32 u = __float_as_uint(f);
    u32 r = (u + 0x7FFFu + ((u >> 16) & 1u)) >> 16;
    return (u16)r;
}
__device__ __forceinline__ float bflo(u32 v) { return __uint_as_float(v << 16); }
__device__ __forceinline__ float bfhi(u32 v) { return __uint_as_float(v & 0xFFFF0000u); }

// ---------------- fp32 -> bf16 mirror of x ----------------
__global__ __launch_bounds__(256) void cvt_x_kernel(const float* __restrict__ x,
                                                    u16* __restrict__ xb) {
    size_t i4 = (size_t)blockIdx.x * 256 + threadIdx.x;   // one float4 / thread
    float4 v = ((const float4*)x)[i4];
    u32 lo = (u32)f2bf(v.x) | ((u32)f2bf(v.y) << 16);
    u32 hi = (u32)f2bf(v.z) | ((u32)f2bf(v.w) << 16);
    ((uint2*)xb)[i4] = make_uint2(lo, hi);
}

// ---------------- CSR build ----------------
__global__ void zero_ints_kernel(int* p, int n) {
    int i = blockIdx.x * blockDim.x + threadIdx.x;
    if (i < n) p[i] = 0;
}

__global__ void count_deg_kernel(const int* __restrict__ dst, int* __restrict__ deg) {
    int e = blockIdx.x * blockDim.x + threadIdx.x;
    if (e < N_EDGES) atomicAdd(&deg[dst[e]], 1);
}

__global__ __launch_bounds__(SCAN_BLOCK) void scan1_kernel(const int* __restrict__ deg,
                                                           int* __restrict__ incl,
                                                           int* __restrict__ bsum) {
    __shared__ int buf[SCAN_BLOCK];
    int t = threadIdx.x;
    int i = blockIdx.x * SCAN_BLOCK + t;
    int v = (i < N_NODES) ? deg[i] : 0;
    buf[t] = v;
    __syncthreads();
    for (int off = 1; off < SCAN_BLOCK; off <<= 1) {
        int tv = (t >= off) ? buf[t - off] : 0;
        __syncthreads();
        buf[t] += tv;
        __syncthreads();
    }
    if (i < N_NODES) incl[i] = buf[t];
    if (t == SCAN_BLOCK - 1) bsum[blockIdx.x] = buf[t];
}

__global__ void scan2_kernel(const int* __restrict__ bsum, int* __restrict__ bpre) {
    if (threadIdx.x == 0) {
        int run = 0;
        for (int i = 0; i < SCAN_NBLK; i++) { bpre[i] = run; run += bsum[i]; }
        bpre[SCAN_NBLK] = run;
    }
}

__global__ __launch_bounds__(SCAN_BLOCK) void scan3_kernel(const int* __restrict__ incl,
                                                           const int* __restrict__ deg,
                                                           const int* __restrict__ bpre,
                                                           int* __restrict__ offsets) {
    int i = blockIdx.x * SCAN_BLOCK + threadIdx.x;
    if (i < N_NODES) offsets[i] = bpre[blockIdx.x] + incl[i] - deg[i];
    if (blockIdx.x == 0 && threadIdx.x == 0) offsets[N_NODES] = bpre[SCAN_NBLK];
}

__global__ void fill_adj_kernel(const int* __restrict__ src, const int* __restrict__ dst,
                                const int* __restrict__ offsets, int* __restrict__ cursor,
                                int* __restrict__ adj) {
    int e = blockIdx.x * blockDim.x + threadIdx.x;
    if (e < N_EDGES) {
        int d = dst[e];
        int p = atomicAdd(&cursor[d], 1);
        adj[offsets[d] + p] = src[e];
    }
}

// ---------------- aggregation (bf16 in, bf16 out): one wave per node ----------------
__global__ __launch_bounds__(256) void agg_kernel(const u16* __restrict__ X,
                                                  const int* __restrict__ offsets,
                                                  const int* __restrict__ adj,
                                                  u16* __restrict__ out) {
    int node = blockIdx.x * 4 + (threadIdx.x >> 6);
    int l = threadIdx.x & 63;                    // lane handles 2 features
    const u32* Xu = (const u32*)X;
    u32 v = Xu[(size_t)node * 64 + l];
    float s0 = bflo(v), s1 = bfhi(v);
    int b = offsets[node], e = offsets[node + 1];
    for (int k = b; k < e; k++) {
        u32 u = Xu[(size_t)adj[k] * 64 + l];
        s0 += bflo(u);
        s1 += bfhi(u);
    }
    ((u32*)out)[(size_t)node * 64 + l] = (u32)f2bf(s0) | ((u32)f2bf(s1) << 16);
}

// ---------------- bf16 MFMA GEMM: out[N x 128] = A[N x 128] @ W[128 x 128] + bias ----------------
// A: bf16 row-major. Wt: bf16 TRANSPOSED [col][k]. Fuses per-block BN column stats.
// OUT_BF16=1 -> bf16 output; 0 -> fp32 output.
template <int OUT_BF16>
__global__ __launch_bounds__(256) void gemm_mfma_kernel(const u16* __restrict__ A,
                                                        const u16* __restrict__ Wt,
                                                        const float* __restrict__ bias,
                                                        void* __restrict__ outp,
                                                        float* __restrict__ psum,
                                                        float* __restrict__ psq, int nrows) {
    __shared__ __align__(16) u16 sA[16384];  // [row][k] swizzled, 32 KB
    __shared__ __align__(16) u16 sW[16384];  // [col][k] swizzled, 32 KB

    int tid = threadIdx.x;
    int rb = blockIdx.x * 128;

    // stage W
    {
        const uint4* g = (const uint4*)Wt;
#pragma unroll
        for (int p = 0; p < 8; p++) {
            int q = p * 256 + tid;
            int r = q >> 4, seg = q & 15;
            uint4 v = g[q];
            *(uint4*)((char*)sW + r * 256 + ((seg * 16) ^ ((r & 7) << 4))) = v;
        }
    }
    // stage A tile (128 rows)
    {
#pragma unroll
        for (int p = 0; p < 8; p++) {
            int q = p * 256 + tid;
            int r = q >> 4, seg = q & 15;
            int grow = rb + r;
            uint4 v = make_uint4(0, 0, 0, 0);
            if (grow < nrows) v = *(const uint4*)(A + (size_t)grow * 128 + seg * 8);
            *(uint4*)((char*)sA + r * 256 + ((seg * 16) ^ ((r & 7) << 4))) = v;
        }
    }
    __syncthreads();

    int l = tid & 63, w = tid >> 6;
    int lr = l & 15, lg = l >> 4;

    f32x4 acc[2][8];
#pragma unroll
    for (int t = 0; t < 2; t++)
#pragma unroll
        for (int c = 0; c < 8; c++) acc[t][c] = (f32x4){0.f, 0.f, 0.f, 0.f};

#pragma unroll
    for (int kc = 0; kc < 4; kc++) {
        int kb2 = (kc * 32 + lg * 8) * 2;   // byte offset along k
        bf16x8 a[2], b[8];
#pragma unroll
        for (int t = 0; t < 2; t++) {
            int row = w * 32 + t * 16 + lr;
            a[t] = *(const bf16x8*)((const char*)sA + row * 256 + (kb2 ^ ((row & 7) << 4)));
        }
#pragma unroll
        for (int c = 0; c < 8; c++) {
            int col = c * 16 + lr;
            b[c] = *(const bf16x8*)((const char*)sW + col * 256 + (kb2 ^ ((col & 7) << 4)));
        }
#pragma unroll
        for (int t = 0; t < 2; t++)
#pragma unroll
            for (int c = 0; c < 8; c++)
                acc[t][c] = __builtin_amdgcn_mfma_f32_16x16x32_bf16(a[t], b[c], acc[t][c], 0, 0, 0);
    }

    // epilogue: bias add, store, per-lane column stats
    float bb[8];
#pragma unroll
    for (int c = 0; c < 8; c++) bb[c] = bias[c * 16 + lr];

    float sp[8], qp[8];
#pragma unroll
    for (int c = 0; c < 8; c++) { sp[c] = 0.f; qp[c] = 0.f; }

    float* outF = (float*)outp;
    u16* outB = (u16*)outp;
#pragma unroll
    for (int t = 0; t < 2; t++) {
#pragma unroll
        for (int r = 0; r < 4; r++) {
            int grow = rb + w * 32 + t * 16 + lg * 4 + r;
            bool ok = grow < nrows;
#pragma unroll
            for (int c = 0; c < 8; c++) {
                float v = acc[t][c][r] + bb[c];
                if (ok) {
                    int col = c * 16 + lr;
                    if (OUT_BF16)
                        outB[(size_t)grow * 128 + col] = f2bf(v);
                    else
                        outF[(size_t)grow * 128 + col] = v;
                    sp[c] += v;
                    qp[c] += v * v;
                }
            }
        }
    }
    // reduce across the 4 lane-groups sharing the same col (lanes l, l^16, l^32, l^48)
#pragma unroll
    for (int c = 0; c < 8; c++) {
        sp[c] += __shfl_xor(sp[c], 16); sp[c] += __shfl_xor(sp[c], 32);
        qp[c] += __shfl_xor(qp[c], 16); qp[c] += __shfl_xor(qp[c], 32);
    }
    __syncthreads();                 // sA no longer read; reuse as reduction buffer
    float* sred = (float*)sA;        // [w][c][lr][2] = 4*8*16*2 floats
    if (lg == 0) {
#pragma unroll
        for (int c = 0; c < 8; c++) {
            sred[(((w * 8 + c) * 16) + lr) * 2 + 0] = sp[c];
            sred[(((w * 8 + c) * 16) + lr) * 2 + 1] = qp[c];
        }
    }
    __syncthreads();
    if (tid < 128) {
        int c = tid >> 4, r = tid & 15;
        float s = 0.f, q = 0.f;
#pragma unroll
        for (int ww = 0; ww < 4; ww++) {
            s += sred[(((ww * 8 + c) * 16) + r) * 2 + 0];
            q += sred[(((ww * 8 + c) * 16) + r) * 2 + 1];
        }
        psum[blockIdx.x * 128 + tid] = s;
        psq[blockIdx.x * 128 + tid] = q;
    }
}

// ---------------- BN finalize (reduce per-block partials) ----------------
// mode 0: scale = rsqrt(v+eps)*g ; shift = bt - m*scale
// mode 1: r2=rsqrt(v+eps); a=r2*g; vu=v*a*a; r3=rsqrt(vu+eps); scale=a*r3*og; shift=ob-m*scale
__global__ __launch_bounds__(512) void bn_finalize_kernel(const float* __restrict__ psum,
                                                          const float* __restrict__ psq,
                                                          const float* __restrict__ g,
                                                          const float* __restrict__ bt,
                                                          const float* __restrict__ og,
                                                          const float* __restrict__ ob,
                                                          float* __restrict__ scale,
                                                          float* __restrict__ shift, int mode) {
    __shared__ float ss[4][128], sq[4][128];
    int f = threadIdx.x & 127;
    int grp = threadIdx.x >> 7;
    float s = 0.f, q = 0.f;
    for (int b = grp; b < GEMM_BLOCKS; b += 4) {
        s += psum[b * 128 + f];
        q += psq[b * 128 + f];
    }
    ss[grp][f] = s; sq[grp][f] = q;
    __syncthreads();
    if (threadIdx.x < 128) {
        s = ss[0][f] + ss[1][f] + ss[2][f] + ss[3][f];
        q = sq[0][f] + sq[1][f] + sq[2][f] + sq[3][f];
        float m = s / (float)N_NODES;
        float v = q / (float)N_NODES - m * m;
        if (v < 0.f) v = 0.f;
        float sc, sh;
        if (mode == 0) {
            float r = rsqrtf(v + BN_EPS);
            sc = r * g[f];
            sh = bt[f] - m * sc;
        } else {
            float r2 = rsqrtf(v + BN_EPS);
            float a = r2 * g[f];
            float vu = v * a * a;
            float r3 = rsqrtf(vu + BN_EPS);
            sc = a * r3 * og[f];
            sh = ob[f] - m * sc;
        }
        scale[f] = sc;
        shift[f] = sh;
    }
}

// ---------------- weight prep ----------------
// W1t[j][k] = bf16(W1[k][j])
__global__ void w1_prep_kernel(const float* __restrict__ W, u16* __restrict__ Wt) {
    int q = blockIdx.x * 256 + threadIdx.x;   // 64 blocks x 256 = 16384
    int j = q >> 7, k = q & 127;
    Wt[q] = f2bf(W[k * 128 + j]);
}

// W2ft[j][k] = bf16(scale1[k]*W2[k][j]);  b2f[j] = b2[j] + sum_k shift1[k]*W2[k][j]
__global__ void fold_w2_kernel(const float* __restrict__ W2, const float* __restrict__ b2,
                               const float* __restrict__ scale1, const float* __restrict__ shift1,
                               u16* __restrict__ W2ft, float* __restrict__ b2f) {
    int j = threadIdx.x;  // 128 threads, 1 block
    float acc = b2[j];
    for (int k = 0; k < 128; k++) {
        float w = W2[k * 128 + j];
        W2ft[j * 128 + k] = f2bf(scale1[k] * w);
        acc += shift1[k] * w;
    }
    b2f[j] = acc;
}

// ---------------- relu-affine: in-place on H (fp32), also writes bf16 mirror ----------------
__global__ __launch_bounds__(256) void relu_affine_kernel(float* __restrict__ H,
                                                          const float* __restrict__ scale,
                                                          const float* __restrict__ shift,
                                                          u16* __restrict__ xb) {
    size_t i4 = (size_t)blockIdx.x * 256 + threadIdx.x;   // one float4 / thread
    int fb = ((int)(i4 & 31)) * 4;
    float4 h = ((const float4*)H)[i4];
    float4 sc = *(const float4*)&scale[fb];
    float4 sh = *(const float4*)&shift[fb];
    float4 y;
    y.x = fmaxf(h.x * sc.x + sh.x, 0.f);
    y.y = fmaxf(h.y * sc.y + sh.y, 0.f);
    y.z = fmaxf(h.z * sc.z + sh.z, 0.f);
    y.w = fmaxf(h.w * sc.w + sh.w, 0.f);
    ((float4*)H)[i4] = y;
    u32 lo = (u32)f2bf(y.x) | ((u32)f2bf(y.y) << 16);
    u32 hi = (u32)f2bf(y.z) | ((u32)f2bf(y.w) << 16);
    ((uint2*)xb)[i4] = make_uint2(lo, hi);
}

// ---------------- readout ----------------
__global__ __launch_bounds__(128) void graph_embed_part_kernel(const float* __restrict__ X,
                                                               const float* __restrict__ w,
                                                               const int* __restrict__ batch,
                                                               float* __restrict__ gpart) {
    int g = blockIdx.x;
    int sl = blockIdx.y;
    int f = threadIdx.x;
    int lo = 0, hi = N_NODES;
    while (lo < hi) { int mid = (lo + hi) >> 1; if (batch[mid] < g) lo = mid + 1; else hi = mid; }
    int s = lo;
    lo = 0; hi = N_NODES;
    while (lo < hi) { int mid = (lo + hi) >> 1; if (batch[mid] < g + 1) lo = mid + 1; else hi = mid; }
    int e = lo;
    int cnt = e - s;
    int per = (cnt + GE_SLICES - 1) / GE_SLICES;
    int rs = s + sl * per;
    int re = rs + per; if (re > e) re = e;
    float acc = 0.f;
    for (int r = rs; r < re; r++) acc += X[(size_t)r * DF + f] * w[r];
    gpart[((size_t)g * GE_SLICES + sl) * DF + f] = acc;
}

__global__ __launch_bounds__(128) void graph_embed_reduce_kernel(const float* __restrict__ gpart,
                                                                 float* __restrict__ ge) {
    int g = blockIdx.x, f = threadIdx.x;
    float a = 0.f;
#pragma unroll
    for (int s = 0; s < GE_SLICES; s++) a += gpart[((size_t)g * GE_SLICES + s) * DF + f];
    ge[g * DF + f] = a;
}

__global__ void final_fc_kernel(const float* __restrict__ ge, const float* __restrict__ fcW,
                                const float* __restrict__ fcb, float* __restrict__ out) {
    int idx = blockIdx.x * blockDim.x + threadIdx.x;  // G*C = 256
    if (idx < NG * NC) {
        int g = idx / NC, c = idx % NC;
        float acc = fcb[c];
        for (int d = 0; d < DF; d++) acc += ge[g * DF + d] * fcW[d * NC + c];
        out[idx] = acc;
    }
}

// ---------------- launcher ----------------
extern "C" void kernel_launch(void* const* d_in, const int* in_sizes, int n_in,
                              void* d_out, int out_size, void* d_ws, size_t ws_size,
                              hipStream_t stream) {
    const float* x    = (const float*)d_in[0];
    const int*   ei   = (const int*)d_in[1];
    const int*   src  = ei;
    const int*   dst  = ei + N_EDGES;
    const float* nw   = (const float*)d_in[2];
    const int*   batch= (const int*)d_in[3];
    const float* W1   = (const float*)d_in[4];
    const float* b1   = (const float*)d_in[5];
    const float* g1   = (const float*)d_in[6];
    const float* bt1  = (const float*)d_in[7];
    const float* W2   = (const float*)d_in[8];
    const float* b2   = (const float*)d_in[9];
    const float* g2   = (const float*)d_in[10];
    const float* bt2  = (const float*)d_in[11];
    const float* og   = (const float*)d_in[12];
    const float* ob   = (const float*)d_in[13];
    const float* fcW  = (const float*)d_in[14];
    const float* fcb  = (const float*)d_in[15];

    float* out_f    = (float*)d_out;
    float* node_out = out_f;                              // N*DF fp32 (also H2 buffer)
    float* ge       = out_f + (size_t)N_NODES * DF;       // G*DF
    float* cls      = ge + NG * DF;                       // G*C

    char* w = (char*)d_ws;
    auto alloc = [&](size_t bytes) { char* p = w; w += (bytes + 255) & ~(size_t)255; return p; };

    u16*   XB      = (u16*)alloc((size_t)N_NODES * DF * 2);     // bf16 node features
    u16*   AGG     = (u16*)alloc((size_t)N_NODES * DF * 2);     // bf16 agg output
    u16*   H1      = (u16*)alloc((size_t)N_NODES * DF * 2);     // bf16 h1_raw
    int*   degcur  = (int*)alloc((size_t)2 * N_NODES * 4);
    int*   deg     = degcur;
    int*   cursor  = degcur + N_NODES;
    int*   offsets = (int*)alloc((size_t)(N_NODES + 1) * 4);
    int*   incl    = (int*)alloc((size_t)N_NODES * 4);
    int*   bsum    = (int*)alloc((SCAN_NBLK + 1) * 4);
    int*   bpre    = (int*)alloc((SCAN_NBLK + 1) * 4);
    int*   adj     = (int*)alloc((size_t)N_EDGES * 4);
    float* psum    = (float*)alloc((size_t)GEMM_BLOCKS * 128 * 4);
    float* psq     = (float*)alloc((size_t)GEMM_BLOCKS * 128 * 4);
    u16*   W1t     = (u16*)alloc(16384 * 2);
    u16*   W2ft    = (u16*)alloc(16384 * 2);
    float* b2f     = (float*)alloc(128 * 4);
    float* scale1  = (float*)alloc(128 * 4);
    float* shift1  = (float*)alloc(128 * 4);
    float* scaleO  = (float*)alloc(128 * 4);
    float* shiftO  = (float*)alloc(128 * 4);
    float* gpart   = (float*)alloc((size_t)NG * GE_SLICES * DF * 4);

    // bf16 mirror of input x
    cvt_x_kernel<<<12500, 256, 0, stream>>>(x, XB);

    // CSR build
    zero_ints_kernel<<<(2 * N_NODES + 255) / 256, 256, 0, stream>>>(degcur, 2 * N_NODES);
    count_deg_kernel<<<(N_EDGES + 255) / 256, 256, 0, stream>>>(dst, deg);
    scan1_kernel<<<SCAN_NBLK, SCAN_BLOCK, 0, stream>>>(deg, incl, bsum);
    scan2_kernel<<<1, 64, 0, stream>>>(bsum, bpre);
    scan3_kernel<<<SCAN_NBLK, SCAN_BLOCK, 0, stream>>>(incl, deg, bpre, offsets);
    fill_adj_kernel<<<(N_EDGES + 255) / 256, 256, 0, stream>>>(src, dst, offsets, cursor, adj);

    for (int l = 0; l < NL; l++) {
        w1_prep_kernel<<<64, 256, 0, stream>>>(W1 + (size_t)l * DF * DF, W1t);
        // agg = X + sum_{in-edges} X[src]   (bf16)
        agg_kernel<<<N_NODES / 4, 256, 0, stream>>>(XB, offsets, adj, AGG);
        // h1_raw = agg @ W1 + b1  (bf16 out) + fused BN1 stats
        gemm_mfma_kernel<1><<<GEMM_BLOCKS, 256, 0, stream>>>(AGG, W1t, b1 + l * DF,
                                                             H1, psum, psq, N_NODES);
        bn_finalize_kernel<<<1, 512, 0, stream>>>(psum, psq, g1 + l * DF, bt1 + l * DF,
                                                  nullptr, nullptr, scale1, shift1, 0);
        fold_w2_kernel<<<1, 128, 0, stream>>>(W2 + (size_t)l * DF * DF, b2 + l * DF,
                                              scale1, shift1, W2ft, b2f);
        // h2_raw = h1_raw @ (BN1-folded W2) + b2f  (fp32 out to node_out) + fused stats
        gemm_mfma_kernel<0><<<GEMM_BLOCKS, 256, 0, stream>>>(H1, W2ft, b2f,
                                                             node_out, psum, psq, N_NODES);
        bn_finalize_kernel<<<1, 512, 0, stream>>>(psum, psq, g2 + l * DF, bt2 + l * DF,
                                                  og + l * DF, ob + l * DF, scaleO, shiftO, 1);
        // x = relu(BN(h2))  in-place on node_out, bf16 mirror into XB
        relu_affine_kernel<<<12500, 256, 0, stream>>>(node_out, scaleO, shiftO, XB);
    }

    graph_embed_part_kernel<<<dim3(NG, GE_SLICES), 128, 0, stream>>>(node_out, nw, batch, gpart);
    graph_embed_reduce_kernel<<<NG, 128, 0, stream>>>(gpart, ge);
    final_fc_kernel<<<1, 256, 0, stream>>>(ge, fcW, fcb, cls);
}